// Round 6
// baseline (300.050 us; speedup 1.0000x reference)
//
#include <hip/hip_runtime.h>
#include <stdint.h>
#include <math.h>

// Problem constants
#define NTOK 8192   // B*S tokens
#define FIN  4096
#define FOUT 4096
#define PP   512
#define QIN  8
#define QOUT 8
#define NFREQ 257   // P/2+1

// ---------------------------------------------------------------------------
// Packed complex type: ext_vector_type(2) float.  All complex adds/subs and
// the twiddle/einsum algebra are written as <2 x float> vector ops so the
// backend can emit full-rate VOP3P packed math (v_pk_add_f32 / v_pk_fma_f32)
// with swizzles/negations folded into op_sel/neg modifiers.
// ---------------------------------------------------------------------------
typedef float f32x2 __attribute__((ext_vector_type(2)));

__device__ __forceinline__ f32x2 mk2(float a, float b) { f32x2 r; r.x = a; r.y = b; return r; }

// a * t as complex, conjugating t when INV (t = forward twiddle).
//   re = ax*tx - ay*ty' ; im = ax*ty' + ay*tx   (ty' = INV ? -ty : ty)
// Packed: bcast(ax)*(tx,ty') + bcast(ay)*(-ty',tx)
template<int INV>
__device__ __forceinline__ f32x2 twmul(f32x2 a, f32x2 t) {
    const f32x2 tr = INV ? mk2(t.x, -t.y) : t;
    const f32x2 ti = INV ? mk2(t.y, t.x) : mk2(-t.y, t.x);
    return mk2(a.x, a.x) * tr + mk2(a.y, a.y) * ti;
}

// ---------------------------------------------------------------------------
// In-register 8-point DFT over the register index (vector-op form).
// ---------------------------------------------------------------------------
template<int INV>
__device__ __forceinline__ void dft8(f32x2 z[8]) {
    const float S = 0.70710678118654752f;
    f32x2 a0 = z[0] + z[4], a4 = z[0] - z[4];
    f32x2 a1 = z[1] + z[5], a5 = z[1] - z[5];
    f32x2 a2 = z[2] + z[6], a6 = z[2] - z[6];
    f32x2 a3 = z[3] + z[7], a7 = z[3] - z[7];
    f32x2 b0 = a0 + a2, b2 = a0 - a2;
    f32x2 b1 = a1 + a3, b3 = a1 - a3;
    z[0] = b0 + b1;
    z[4] = b0 - b1;
    f32x2 r3 = INV ? mk2(-b3.y, b3.x) : mk2(b3.y, -b3.x);   // (-+i) * b3
    z[2] = b2 + r3;
    z[6] = b2 - r3;
    f32x2 c0 = a4;
    f32x2 c1 = INV ? (S * (a5 + mk2(-a5.y, a5.x)))          // S*(x-y, y+x)
                   : (S * (a5 + mk2(a5.y, -a5.x)));         // S*(x+y, y-x)
    f32x2 c2 = INV ? mk2(-a6.y, a6.x) : mk2(a6.y, -a6.x);
    f32x2 c3 = INV ? (S * (mk2(-a7.y, a7.x) - a7))          // S*(-y-x, x-y)
                   : (S * (mk2(a7.y, -a7.x) - a7));         // S*(y-x, -x-y)
    f32x2 d0 = c0 + c2, d2 = c0 - c2;
    f32x2 d1 = c1 + c3, d3 = c1 - c3;
    z[1] = d0 + d1;
    z[5] = d0 - d1;
    f32x2 r7 = INV ? mk2(-d3.y, d3.x) : mk2(d3.y, -d3.x);
    z[3] = d2 + r7;
    z[7] = d2 - r7;
}

// ---------------------------------------------------------------------------
// Per-wave 512-point FFT, four-step radix-8^3 (natural order in / out).
//   n = 64*n2 + 8*n1 + n0 ; k = k0 + 8*k1 + 64*k2 ; lane = 8h + w
// Scratch plane: 8 rows x 64 cols at stride 68 (padded).  Every DS access is
// base + compile-time immediate; all patterns sit at the wave64-b64
// 4-lanes-per-bank-pair structural floor (see R5 header for the bank math).
// TA64[h*8+k] = W64^{hk} (broadcast).  TBt[k*64+lane] = W512^{(w*(h+8k))&511}.
// Same-wave DS ops are processed in order -> no barriers inside.
// ---------------------------------------------------------------------------
template<int INV>
__device__ __forceinline__ void fft512(f32x2 z[8], f32x2* plane,
                                       const f32x2* TA64, const f32x2* TBt,
                                       const int lane, const int h, const int w,
                                       const int bRd, const int bW2) {
    dft8<INV>(z);                                   // over n2 -> k0
#pragma unroll
    for (int k = 1; k < 8; ++k)
        z[k] = twmul<INV>(z[k], TA64[h * 8 + k]);
#pragma unroll
    for (int k = 0; k < 8; ++k) plane[68 * k + lane] = z[k];     // T1 write
#pragma unroll
    for (int k = 0; k < 8; ++k) z[k] = plane[bRd + 8 * k];       // T1 read
    dft8<INV>(z);                                   // over n1 -> k1
#pragma unroll
    for (int k = 0; k < 8; ++k)
        z[k] = twmul<INV>(z[k], TBt[k * 64 + lane]);
#pragma unroll
    for (int k = 0; k < 8; ++k) plane[68 * k + bW2] = z[k];      // T2 write
#pragma unroll
    for (int k = 0; k < 8; ++k) z[k] = plane[bRd + 8 * k];       // T2 read
    dft8<INV>(z);                                   // over n0 -> k2
}

// ---------------------------------------------------------------------------
// Cheap exact-enough GELU: A&S 7.1.26 erf (|eps| <= 1.5e-7), rcp + exp + 5 fma.
// ---------------------------------------------------------------------------
__device__ __forceinline__ float gelu_f(float v) {
    const float a = fabsf(v) * 0.70710678118654752f;
    const float t = __builtin_amdgcn_rcpf(fmaf(0.3275911f, a, 1.0f));
    float p = fmaf(1.061405429f, t, -1.453152027f);
    p = fmaf(p, t, 1.421413741f);
    p = fmaf(p, t, -0.284496736f);
    p = fmaf(p, t, 0.254829592f);
    p = p * t;
    const float e = __expf(-a * a);
    float erfa = fmaf(-p, e, 1.0f);         // erf(|v|/sqrt2)
    erfa = copysignf(erfa, v);
    return 0.5f * v * (1.0f + erfa);
}

// ---------------------------------------------------------------------------
// wf_build: Wf4[(o*4+i2)*257 + f] = float4{ Wf[o][2*i2][f], Wf[o][2*i2+1][f] }
// Scale = 1/1024: 1/512 (irfft norm) x 1/2 (Hermitian-unpack halves folded).
// ---------------------------------------------------------------------------
__global__ __launch_bounds__(256) void wf_build(const float* __restrict__ w,
                                                float4* __restrict__ Wf4) {
    __shared__ float  sw[512];
    __shared__ float2 tb[512];          // tb[k] = W^k = (cos, -sin)(2pi k/512)
    __shared__ float2 red[4][64];
    const int blk = blockIdx.x;         // o*8 + i
    const float* wrow = w + (size_t)blk * 512;
    const int t   = threadIdx.x;
    const int fi  = t & 63;
    const int seg = t >> 6;
    sw[t]       = wrow[t];
    sw[t + 256] = wrow[t + 256];
    const float th = -6.283185307179586f / 512.0f;
    {
        float a0 = th * (float)t, a1 = th * (float)(t + 256);
        tb[t]       = make_float2(cosf(a0), sinf(a0));
        tb[t + 256] = make_float2(cosf(a1), sinf(a1));
    }
    __syncthreads();
    const int o = blk >> 3, i = blk & 7;
    float2* dst_base = (float2*)Wf4 + (i & 1);      // float4 slot = 2 float2
    for (int g = 0; g < 5; ++g) {
        const int f = (g < 4) ? (g * 64 + fi) : 256;
        float re = 0.f, im = 0.f;
        int idx = (f * (seg * 128)) & 511;
        for (int n = 0; n < 128; ++n) {
            const float2 e = tb[idx];
            const float  v = sw[seg * 128 + n];
            re += v * e.x;
            im += v * e.y;
            idx = (idx + f) & 511;
        }
        red[seg][fi] = make_float2(re, im);
        __syncthreads();
        if (seg == 0) {
            float2 r0 = red[0][fi], r1 = red[1][fi], r2 = red[2][fi], r3 = red[3][fi];
            float rre = (r0.x + r1.x) + (r2.x + r3.x);
            float rim = (r0.y + r1.y) + (r2.y + r3.y);
            if (g < 4 || fi == 0)
                dst_base[((size_t)(o * 4 + (i >> 1)) * 257 + f) * 2] =
                    make_float2(rre * (1.f / 1024.f), rim * (1.f / 1024.f));
        }
        __syncthreads();
    }
}

// ---------------------------------------------------------------------------
// fft_conv: one block (256 thr, 4 waves) per token.  Wave c handles packed
// complex sequence Z_c = xs[2c] + i*xs[2c+1].
// LDS (f32x2 units), 2752 total = 22016 B:
//   planes [0,2176)    : wave*544 — padded-68 FFT scratch; slots [0,512) also
//                        hold spectra (natural n) and einsum output (in-place)
//   TA64  [2176,2240)  : h*8+k -> W64^{hk}
//   TBt   [2240,2752)  : k*64+lane -> W512^{(w*(h+8k))&511}
// __launch_bounds__: no 2nd arg — (256,w) caps VGPR at 256/w on this
// toolchain and anything <=64 VGPR spills hundreds of MB (R2/R3 counters).
// ---------------------------------------------------------------------------
__global__ __launch_bounds__(256) void fft_conv(const float* __restrict__ x,
                                                const int* __restrict__ sign_bits,
                                                const float4* __restrict__ Wf4,
                                                const float* __restrict__ bias,
                                                float* __restrict__ out) {
    __shared__ f32x2 LB[2752];

    const int tid  = threadIdx.x;
    const int wave = tid >> 6;
    const int lane = tid & 63;
    const int h = lane >> 3, w = lane & 7;
    const int bRd = 68 * h + w;          // fft512 transpose-read base
    const int bW2 = 8 * w + h;           // fft512 T2-write col base
    const float* xin  = x   + (size_t)blockIdx.x * FIN;
    float*       yout = out + (size_t)blockIdx.x * FOUT;

    // ---- twiddle tables (HW sincos) ----
    {
        const float th = -6.283185307179586f / 512.0f;
        if (tid < 64) {                  // TA64[h*8+k] = W64^{hk} = W512^{8hk}
            const int hh = tid >> 3, kk = tid & 7;
            float sn, cs;
            __sincosf(th * (float)(8 * hh * kk), &sn, &cs);
            LB[2176 + tid] = mk2(cs, sn);
        }
        for (int j = tid; j < 512; j += 256) {   // TBt
            const int k = j >> 6, l = j & 63;
            const int e = ((l & 7) * ((l >> 3) + 8 * k)) & 511;
            float sn, cs;
            __sincosf(th * (float)e, &sn, &cs);
            LB[2240 + j] = mk2(cs, sn);
        }
    }
    __syncthreads();

    const f32x2* TA64 = &LB[2176];
    const f32x2* TBt  = &LB[2240];
    f32x2* plane = &LB[wave * 544];      // wave-private scratch + spectra

    // ---- pack x*sign into registers (reg k = element 64k+lane) ----
    f32x2 z[8];
    {
        const float* xre = xin + (2 * wave) * 512;
        const float* xim = xin + (2 * wave + 1) * 512;
        const int*   sre = sign_bits + (2 * wave) * 512;
        const int*   sim = sign_bits + (2 * wave + 1) * 512;
#pragma unroll
        for (int k = 0; k < 8; ++k) {
            const int p = 64 * k + lane;
            float a = xre[p], b = xim[p];
            unsigned sa = (unsigned)sre[p] << 31;
            unsigned sb = (unsigned)sim[p] << 31;
            z[k] = mk2(__uint_as_float(__float_as_uint(a) ^ sa),
                       __uint_as_float(__float_as_uint(b) ^ sb));
        }
    }

    // ---- forward FFT (wave-private) ----
    fft512<0>(z, plane, TA64, TBt, lane, h, w, bRd, bW2);

#pragma unroll
    for (int k = 0; k < 8; ++k) plane[64 * k + lane] = z[k];     // spectra
    __syncthreads();

    // ---- spectral einsum, in place (thread f owns slots {f, 512-f}) ----
    for (int f = tid; f <= 256; f += 256) {     // thread 0 also does f=256
        const int fm = (512 - f) & 511;
        f32x2 Xf[8];
#pragma unroll
        for (int c = 0; c < 4; ++c) {
            const f32x2 zp = LB[c * 544 + f];
            const f32x2 zm = LB[c * 544 + fm];
            // halves folded into Wf4 (wf_build scale 1/1024)
            Xf[2 * c]     = zp + mk2(zm.x, -zm.y);               // zp + conj(zm)
            Xf[2 * c + 1] = mk2(zp.y, -zp.x) + mk2(zm.y, zm.x);  // -i*zp + i*conj(zm)
        }
        const float4* wf = Wf4 + f;
        f32x2 Y[8];
#pragma unroll
        for (int o = 0; o < 8; ++o) {
            f32x2 acc = mk2(0.f, 0.f);
#pragma unroll
            for (int i2 = 0; i2 < 4; ++i2) {
                const float4 wv = wf[(o * 4 + i2) * 257];    // coalesced dwordx4
                const f32x2 x0 = Xf[2 * i2], x1 = Xf[2 * i2 + 1];
                acc += mk2(x0.x, x0.x) * mk2(wv.x, wv.y);
                acc += mk2(x0.y, x0.y) * mk2(-wv.y, wv.x);
                acc += mk2(x1.x, x1.x) * mk2(wv.z, wv.w);
                acc += mk2(x1.y, x1.y) * mk2(-wv.w, wv.z);
            }
            Y[o] = acc;
        }
#pragma unroll
        for (int c = 0; c < 4; ++c) {
            const f32x2 y0 = Y[2 * c], y1 = Y[2 * c + 1];
            LB[c * 544 + f] = y0 + mk2(-y1.y, y1.x);             // y0 + i*y1
            if (f != 0 && f != 256)
                LB[c * 544 + 512 - f] = mk2(y0.x, -y0.y) + mk2(y1.y, y1.x);
        }
    }
    __syncthreads();

    // ---- inverse FFT (reads own plane, then scratch clobbers it) ----
#pragma unroll
    for (int k = 0; k < 8; ++k) z[k] = plane[64 * k + lane];

    fft512<1>(z, plane, TA64, TBt, lane, h, w, bRd, bW2);

    // ---- epilogue: bias + GELU (A&S erf), coalesced stores ----
    {
        const float* bre = bias + (2 * wave) * 512;
        const float* bim = bias + (2 * wave + 1) * 512;
        float* yre = yout + (2 * wave) * 512;
        float* yim = yout + (2 * wave + 1) * 512;
#pragma unroll
        for (int k = 0; k < 8; ++k) {
            const int p = 64 * k + lane;
            yre[p] = gelu_f(z[k].x + bre[p]);
            yim[p] = gelu_f(z[k].y + bim[p]);
        }
    }
}

extern "C" void kernel_launch(void* const* d_in, const int* in_sizes, int n_in,
                              void* d_out, int out_size, void* d_ws, size_t ws_size,
                              hipStream_t stream) {
    const float* x        = (const float*)d_in[0];   // [B,S,F_IN] fp32
    const float* w        = (const float*)d_in[1];   // [QOUT,QIN,P] fp32
    const float* bias     = (const float*)d_in[2];   // [F_OUT] fp32
    const int*  sign_bits = (const int*)d_in[3];     // [F_IN] int32
    float* out = (float*)d_out;                      // [B,S,F_OUT] fp32

    float4* Wf4 = (float4*)d_ws;                     // [32][257] float4 = 131.6 KB

    wf_build<<<QOUT * QIN, 256, 0, stream>>>(w, Wf4);
    fft_conv<<<NTOK, 256, 0, stream>>>(x, sign_bits, Wf4, bias, out);
}

// Round 7
// 285.067 us; speedup vs baseline: 1.0526x; 1.0526x over previous
//
#include <hip/hip_runtime.h>
#include <stdint.h>
#include <math.h>

// Problem constants
#define NTOK 8192   // B*S tokens
#define FIN  4096
#define FOUT 4096
#define PP   512
#define QIN  8
#define QOUT 8
#define NFREQ 257   // P/2+1

// ---------------------------------------------------------------------------
// Packed complex type: ext_vector_type(2) float -> VOP3P packed math.
// ---------------------------------------------------------------------------
typedef float f32x2 __attribute__((ext_vector_type(2)));

__device__ __forceinline__ f32x2 mk2(float a, float b) { f32x2 r; r.x = a; r.y = b; return r; }

// a * t as complex, conjugating t when INV (t = forward twiddle).
template<int INV>
__device__ __forceinline__ f32x2 twmul(f32x2 a, f32x2 t) {
    const f32x2 tr = INV ? mk2(t.x, -t.y) : t;
    const f32x2 ti = INV ? mk2(t.y, t.x) : mk2(-t.y, t.x);
    return mk2(a.x, a.x) * tr + mk2(a.y, a.y) * ti;
}

// ---------------------------------------------------------------------------
// In-register 8-point DFT over the register index (vector-op form).
// ---------------------------------------------------------------------------
template<int INV>
__device__ __forceinline__ void dft8(f32x2 z[8]) {
    const float S = 0.70710678118654752f;
    f32x2 a0 = z[0] + z[4], a4 = z[0] - z[4];
    f32x2 a1 = z[1] + z[5], a5 = z[1] - z[5];
    f32x2 a2 = z[2] + z[6], a6 = z[2] - z[6];
    f32x2 a3 = z[3] + z[7], a7 = z[3] - z[7];
    f32x2 b0 = a0 + a2, b2 = a0 - a2;
    f32x2 b1 = a1 + a3, b3 = a1 - a3;
    z[0] = b0 + b1;
    z[4] = b0 - b1;
    f32x2 r3 = INV ? mk2(-b3.y, b3.x) : mk2(b3.y, -b3.x);   // (-+i) * b3
    z[2] = b2 + r3;
    z[6] = b2 - r3;
    f32x2 c0 = a4;
    f32x2 c1 = INV ? (S * (a5 + mk2(-a5.y, a5.x)))
                   : (S * (a5 + mk2(a5.y, -a5.x)));
    f32x2 c2 = INV ? mk2(-a6.y, a6.x) : mk2(a6.y, -a6.x);
    f32x2 c3 = INV ? (S * (mk2(-a7.y, a7.x) - a7))
                   : (S * (mk2(a7.y, -a7.x) - a7));
    f32x2 d0 = c0 + c2, d2 = c0 - c2;
    f32x2 d1 = c1 + c3, d3 = c1 - c3;
    z[1] = d0 + d1;
    z[5] = d0 - d1;
    f32x2 r7 = INV ? mk2(-d3.y, d3.x) : mk2(d3.y, -d3.x);
    z[3] = d2 + r7;
    z[7] = d2 - r7;
}

// ---------------------------------------------------------------------------
// Per-wave 512-point FFT, four-step radix-8^3 (natural order in / out).
//   n = 64*n2 + 8*n1 + n0 ; k = k0 + 8*k1 + 64*k2 ; lane = 8h + w
// Scratch plane: 8 rows x 64 cols at stride 68 (padded).  Every DS access is
// base + compile-time immediate; all patterns sit at the wave64-b64
// 4-lanes-per-bank-pair structural floor (see R5 header for the bank math).
// TA64[h*8+k] = W64^{hk} (broadcast).  TBt[k*64+lane] = W512^{(w*(h+8k))&511}.
// Same-wave DS ops are processed in order -> no barriers inside.
// ---------------------------------------------------------------------------
template<int INV>
__device__ __forceinline__ void fft512(f32x2 z[8], f32x2* plane,
                                       const f32x2* TA64, const f32x2* TBt,
                                       const int lane, const int h, const int w,
                                       const int bRd, const int bW2) {
    dft8<INV>(z);                                   // over n2 -> k0
#pragma unroll
    for (int k = 1; k < 8; ++k)
        z[k] = twmul<INV>(z[k], TA64[h * 8 + k]);
#pragma unroll
    for (int k = 0; k < 8; ++k) plane[68 * k + lane] = z[k];     // T1 write
#pragma unroll
    for (int k = 0; k < 8; ++k) z[k] = plane[bRd + 8 * k];       // T1 read
    dft8<INV>(z);                                   // over n1 -> k1
#pragma unroll
    for (int k = 0; k < 8; ++k)
        z[k] = twmul<INV>(z[k], TBt[k * 64 + lane]);
#pragma unroll
    for (int k = 0; k < 8; ++k) plane[68 * k + bW2] = z[k];      // T2 write
#pragma unroll
    for (int k = 0; k < 8; ++k) z[k] = plane[bRd + 8 * k];       // T2 read
    dft8<INV>(z);                                   // over n0 -> k2
}

// ---------------------------------------------------------------------------
// Cheap exact-enough GELU: A&S 7.1.26 erf (|eps| <= 1.5e-7), rcp + exp + 5 fma.
// ---------------------------------------------------------------------------
__device__ __forceinline__ float gelu_f(float v) {
    const float a = fabsf(v) * 0.70710678118654752f;
    const float t = __builtin_amdgcn_rcpf(fmaf(0.3275911f, a, 1.0f));
    float p = fmaf(1.061405429f, t, -1.453152027f);
    p = fmaf(p, t, 1.421413741f);
    p = fmaf(p, t, -0.284496736f);
    p = fmaf(p, t, 0.254829592f);
    p = p * t;
    const float e = __expf(-a * a);
    float erfa = fmaf(-p, e, 1.0f);         // erf(|v|/sqrt2)
    erfa = copysignf(erfa, v);
    return 0.5f * v * (1.0f + erfa);
}

// ---------------------------------------------------------------------------
// wf_build: Wf4[(o*4+i2)*257 + f] = float4{ Wf[o][2*i2][f], Wf[o][2*i2+1][f] }
// Scale = 1/1024: 1/512 (irfft norm) x 1/2 (Hermitian-unpack halves folded).
// ---------------------------------------------------------------------------
__global__ __launch_bounds__(256) void wf_build(const float* __restrict__ w,
                                                float4* __restrict__ Wf4) {
    __shared__ float  sw[512];
    __shared__ float2 tb[512];          // tb[k] = W^k = (cos, -sin)(2pi k/512)
    __shared__ float2 red[4][64];
    const int blk = blockIdx.x;         // o*8 + i
    const float* wrow = w + (size_t)blk * 512;
    const int t   = threadIdx.x;
    const int fi  = t & 63;
    const int seg = t >> 6;
    sw[t]       = wrow[t];
    sw[t + 256] = wrow[t + 256];
    const float th = -6.283185307179586f / 512.0f;
    {
        float a0 = th * (float)t, a1 = th * (float)(t + 256);
        tb[t]       = make_float2(cosf(a0), sinf(a0));
        tb[t + 256] = make_float2(cosf(a1), sinf(a1));
    }
    __syncthreads();
    const int o = blk >> 3, i = blk & 7;
    float2* dst_base = (float2*)Wf4 + (i & 1);      // float4 slot = 2 float2
    for (int g = 0; g < 5; ++g) {
        const int f = (g < 4) ? (g * 64 + fi) : 256;
        float re = 0.f, im = 0.f;
        int idx = (f * (seg * 128)) & 511;
        for (int n = 0; n < 128; ++n) {
            const float2 e = tb[idx];
            const float  v = sw[seg * 128 + n];
            re += v * e.x;
            im += v * e.y;
            idx = (idx + f) & 511;
        }
        red[seg][fi] = make_float2(re, im);
        __syncthreads();
        if (seg == 0) {
            float2 r0 = red[0][fi], r1 = red[1][fi], r2 = red[2][fi], r3 = red[3][fi];
            float rre = (r0.x + r1.x) + (r2.x + r3.x);
            float rim = (r0.y + r1.y) + (r2.y + r3.y);
            if (g < 4 || fi == 0)
                dst_base[((size_t)(o * 4 + (i >> 1)) * 257 + f) * 2] =
                    make_float2(rre * (1.f / 1024.f), rim * (1.f / 1024.f));
        }
        __syncthreads();
    }
}

// ---------------------------------------------------------------------------
// fft_conv: one block (256 thr, 4 waves) per token.  Wave c handles packed
// complex sequence Z_c = xs[2c] + i*xs[2c+1].
// LDS (f32x2 units), 2752 total = 22016 B:
//   planes [0,2176)    : wave*544 — padded-68 FFT scratch; slots [0,512) also
//                        hold spectra (natural n) and einsum output (in-place)
//   TA64  [2176,2240)  : h*8+k -> W64^{hk}
//   TBt   [2240,2752)  : k*64+lane -> W512^{(w*(h+8k))&511}
// __launch_bounds__(256,4): 64-VGPR cap = the occupancy band boundary
// (waves/CU halve at >64).  Natural pressure is 68 after the per-c einsum
// restructure cut peak live regs; expect zero spill — gate on FETCH/WRITE
// staying at 66/131 MB.
// ---------------------------------------------------------------------------
__global__ __launch_bounds__(256, 4) void fft_conv(const float* __restrict__ x,
                                                   const int* __restrict__ sign_bits,
                                                   const float4* __restrict__ Wf4,
                                                   const float* __restrict__ bias,
                                                   float* __restrict__ out) {
    __shared__ f32x2 LB[2752];

    const int tid  = threadIdx.x;
    const int wave = tid >> 6;
    const int lane = tid & 63;
    const int h = lane >> 3, w = lane & 7;
    const int bRd = 68 * h + w;          // fft512 transpose-read base
    const int bW2 = 8 * w + h;           // fft512 T2-write col base
    const float* xin  = x   + (size_t)blockIdx.x * FIN;
    float*       yout = out + (size_t)blockIdx.x * FOUT;

    // ---- twiddle tables (HW sincos) ----
    {
        const float th = -6.283185307179586f / 512.0f;
        if (tid < 64) {                  // TA64[h*8+k] = W64^{hk} = W512^{8hk}
            const int hh = tid >> 3, kk = tid & 7;
            float sn, cs;
            __sincosf(th * (float)(8 * hh * kk), &sn, &cs);
            LB[2176 + tid] = mk2(cs, sn);
        }
        for (int j = tid; j < 512; j += 256) {   // TBt
            const int k = j >> 6, l = j & 63;
            const int e = ((l & 7) * ((l >> 3) + 8 * k)) & 511;
            float sn, cs;
            __sincosf(th * (float)e, &sn, &cs);
            LB[2240 + j] = mk2(cs, sn);
        }
    }
    __syncthreads();

    const f32x2* TA64 = &LB[2176];
    const f32x2* TBt  = &LB[2240];
    f32x2* plane = &LB[wave * 544];      // wave-private scratch + spectra

    // ---- pack x*sign into registers (reg k = element 64k+lane) ----
    f32x2 z[8];
    {
        const float* xre = xin + (2 * wave) * 512;
        const float* xim = xin + (2 * wave + 1) * 512;
        const int*   sre = sign_bits + (2 * wave) * 512;
        const int*   sim = sign_bits + (2 * wave + 1) * 512;
#pragma unroll
        for (int k = 0; k < 8; ++k) {
            const int p = 64 * k + lane;
            float a = xre[p], b = xim[p];
            unsigned sa = (unsigned)sre[p] << 31;
            unsigned sb = (unsigned)sim[p] << 31;
            z[k] = mk2(__uint_as_float(__float_as_uint(a) ^ sa),
                       __uint_as_float(__float_as_uint(b) ^ sb));
        }
    }

    // ---- forward FFT (wave-private) ----
    fft512<0>(z, plane, TA64, TBt, lane, h, w, bRd, bW2);

#pragma unroll
    for (int k = 0; k < 8; ++k) plane[64 * k + lane] = z[k];     // spectra
    __syncthreads();

    // ---- spectral einsum, in place (thread f owns slots {f, 512-f}) ----
    // Per-c processing: only Y[2c],Y[2c+1] live at a time (peak-reg cut);
    // each output = two independent 4-deep packed-fma chains (accA/accB).
    for (int f = tid; f <= 256; f += 256) {     // thread 0 also does f=256
        const int fm = (512 - f) & 511;
        f32x2 Xf[8];
#pragma unroll
        for (int c = 0; c < 4; ++c) {
            const f32x2 zp = LB[c * 544 + f];
            const f32x2 zm = LB[c * 544 + fm];
            // halves folded into Wf4 (wf_build scale 1/1024)
            Xf[2 * c]     = zp + mk2(zm.x, -zm.y);               // zp + conj(zm)
            Xf[2 * c + 1] = mk2(zp.y, -zp.x) + mk2(zm.y, zm.x);  // -i*zp + i*conj(zm)
        }
        const float4* wf = Wf4 + f;
#pragma unroll
        for (int c = 0; c < 4; ++c) {
            f32x2 Y01[2];
#pragma unroll
            for (int oo = 0; oo < 2; ++oo) {
                const int o = 2 * c + oo;
                f32x2 accA = mk2(0.f, 0.f), accB = mk2(0.f, 0.f);
#pragma unroll
                for (int i2 = 0; i2 < 4; i2 += 2) {
                    const float4 wv0 = wf[(o * 4 + i2) * 257];       // dwordx4
                    const float4 wv1 = wf[(o * 4 + i2 + 1) * 257];
                    const f32x2 x0 = Xf[2 * i2],     x1 = Xf[2 * i2 + 1];
                    const f32x2 x2 = Xf[2 * i2 + 2], x3 = Xf[2 * i2 + 3];
                    accA += mk2(x0.x, x0.x) * mk2(wv0.x, wv0.y);
                    accA += mk2(x0.y, x0.y) * mk2(-wv0.y, wv0.x);
                    accA += mk2(x1.x, x1.x) * mk2(wv0.z, wv0.w);
                    accA += mk2(x1.y, x1.y) * mk2(-wv0.w, wv0.z);
                    accB += mk2(x2.x, x2.x) * mk2(wv1.x, wv1.y);
                    accB += mk2(x2.y, x2.y) * mk2(-wv1.y, wv1.x);
                    accB += mk2(x3.x, x3.x) * mk2(wv1.z, wv1.w);
                    accB += mk2(x3.y, x3.y) * mk2(-wv1.w, wv1.z);
                }
                Y01[oo] = accA + accB;
            }
            const f32x2 y0 = Y01[0], y1 = Y01[1];
            LB[c * 544 + f] = y0 + mk2(-y1.y, y1.x);             // y0 + i*y1
            if (f != 0 && f != 256)
                LB[c * 544 + 512 - f] = mk2(y0.x, -y0.y) + mk2(y1.y, y1.x);
        }
    }
    __syncthreads();

    // ---- inverse FFT (reads own plane, then scratch clobbers it) ----
#pragma unroll
    for (int k = 0; k < 8; ++k) z[k] = plane[64 * k + lane];

    fft512<1>(z, plane, TA64, TBt, lane, h, w, bRd, bW2);

    // ---- epilogue: bias + GELU (A&S erf), coalesced stores ----
    {
        const float* bre = bias + (2 * wave) * 512;
        const float* bim = bias + (2 * wave + 1) * 512;
        float* yre = yout + (2 * wave) * 512;
        float* yim = yout + (2 * wave + 1) * 512;
#pragma unroll
        for (int k = 0; k < 8; ++k) {
            const int p = 64 * k + lane;
            yre[p] = gelu_f(z[k].x + bre[p]);
            yim[p] = gelu_f(z[k].y + bim[p]);
        }
    }
}

extern "C" void kernel_launch(void* const* d_in, const int* in_sizes, int n_in,
                              void* d_out, int out_size, void* d_ws, size_t ws_size,
                              hipStream_t stream) {
    const float* x        = (const float*)d_in[0];   // [B,S,F_IN] fp32
    const float* w        = (const float*)d_in[1];   // [QOUT,QIN,P] fp32
    const float* bias     = (const float*)d_in[2];   // [F_OUT] fp32
    const int*  sign_bits = (const int*)d_in[3];     // [F_IN] int32
    float* out = (float*)d_out;                      // [B,S,F_OUT] fp32

    float4* Wf4 = (float4*)d_ws;                     // [32][257] float4 = 131.6 KB

    wf_build<<<QOUT * QIN, 256, 0, stream>>>(w, Wf4);
    fft_conv<<<NTOK, 256, 0, stream>>>(x, sign_bits, Wf4, bias, out);
}